// Round 4
// baseline (120.141 us; speedup 1.0000x reference)
//
#include <hip/hip_runtime.h>

// Sliding 79x69 box-filter mean, SAME zero padding, then (x - mean) / 5.
// Separable: vertical 79-tap sliding sum (float2, 4 waves/SIMD) ->
// horizontal 69-tap sum via wave prefix scan, 2 rows per wave for ILP.

#define HH   512
#define WW   512
#define NIMG 32
#define RH   39   // (79-1)/2
#define RW   34   // (69-1)/2
#define CHUNK 16
#define NCHUNK (HH / CHUNK)   // 32
#define W2 (WW / 2)           // 256 float2 per row

__device__ __forceinline__ float2 add2(float2 a, float2 b) {
    return make_float2(a.x + b.x, a.y + b.y);
}
__device__ __forceinline__ float2 sub2(float2 a, float2 b) {
    return make_float2(a.x - b.x, a.y - b.y);
}

// ---------------------------------------------------------------------------
// Pass 1: vertical sliding sum. Thread = (n, chunk16, w2). float2 per lane,
// 262144 threads (4 waves/SIMD), 4 partial accumulators for ILP.
// ---------------------------------------------------------------------------
__global__ __launch_bounds__(256) void vpass_kernel(const float* __restrict__ xg,
                                                    float* __restrict__ cg) {
    int t  = blockIdx.x * 256 + threadIdx.x;
    int w2 = t & (W2 - 1);
    int c  = (t >> 8) & (NCHUNK - 1);
    int n  = t >> 13;

    const float2* p = (const float2*)xg + (size_t)n * HH * W2 + w2;
    float2*       q = (float2*)cg       + (size_t)n * HH * W2 + w2;
    int h0 = c * CHUNK;

    if (h0 - RH >= 0 && h0 + CHUNK + RH <= HH) {
        // interior: rows [h0-39, h0+55] all in range
        const float2* pr = p + (size_t)(h0 - RH) * W2;
        float2 s0 = make_float2(0, 0), s1 = s0, s2 = s0, s3 = s0;
        #pragma unroll
        for (int i = 0; i < 76; i += 4) {
            s0 = add2(s0, pr[(size_t)(i + 0) * W2]);
            s1 = add2(s1, pr[(size_t)(i + 1) * W2]);
            s2 = add2(s2, pr[(size_t)(i + 2) * W2]);
            s3 = add2(s3, pr[(size_t)(i + 3) * W2]);
        }
        s0 = add2(s0, pr[(size_t)76 * W2]);
        s1 = add2(s1, pr[(size_t)77 * W2]);
        s2 = add2(s2, pr[(size_t)78 * W2]);
        float2 s = add2(add2(s0, s1), add2(s2, s3));
        #pragma unroll
        for (int h = h0; h < h0 + CHUNK; ++h) {
            q[(size_t)h * W2] = s;
            s = add2(s, p[(size_t)(h + RH + 1) * W2]);
            s = sub2(s, p[(size_t)(h - RH) * W2]);
        }
    } else {
        int lo = h0 - RH; if (lo < 0) lo = 0;
        int hi = h0 + RH; if (hi > HH - 1) hi = HH - 1;
        float2 s0 = make_float2(0, 0), s1 = s0, s2 = s0, s3 = s0;
        int i = lo;
        for (; i + 4 <= hi + 1; i += 4) {
            s0 = add2(s0, p[(size_t)(i + 0) * W2]);
            s1 = add2(s1, p[(size_t)(i + 1) * W2]);
            s2 = add2(s2, p[(size_t)(i + 2) * W2]);
            s3 = add2(s3, p[(size_t)(i + 3) * W2]);
        }
        for (; i <= hi; ++i) s0 = add2(s0, p[(size_t)i * W2]);
        float2 s = add2(add2(s0, s1), add2(s2, s3));
        #pragma unroll
        for (int h = h0; h < h0 + CHUNK; ++h) {
            q[(size_t)h * W2] = s;
            int ia = h + RH + 1, ib = h - RH;
            if (ia < HH) s = add2(s, p[(size_t)ia * W2]);
            if (ib >= 0) s = sub2(s, p[(size_t)ib * W2]);
        }
    }
}

// ---------------------------------------------------------------------------
// Pass 2: horizontal 69-tap sum via per-wave prefix scan + finalize.
// TWO rows per wave (independent scan chains interleaved for ILP).
// rowsum[w] = P[min(512, w+35)] - P[max(0, w-34)]  (P = exclusive prefix)
// ---------------------------------------------------------------------------
__global__ __launch_bounds__(256) void hpass_kernel(const float* __restrict__ colsum,
                                                    const float* __restrict__ x,
                                                    float* __restrict__ out) {
    const float INV = 1.0f / (79.0f * 69.0f);

    int gid  = blockIdx.x * 256 + threadIdx.x;
    int wv   = gid >> 6;             // 0 .. NIMG*HH/2-1
    int lane = threadIdx.x & 63;

    size_t base0 = (size_t)(wv * 2) * WW;
    size_t base1 = base0 + WW;

    const float4* tp0 = (const float4*)(colsum + base0);
    const float4* tp1 = (const float4*)(colsum + base1);
    const float4* xp0 = (const float4*)(x + base0);
    const float4* xp1 = (const float4*)(x + base1);
    float4 a0 = tp0[lane * 2];
    float4 a1 = tp0[lane * 2 + 1];
    float4 c0 = tp1[lane * 2];
    float4 c1 = tp1[lane * 2 + 1];
    float4 b0 = xp0[lane * 2];
    float4 b1 = xp0[lane * 2 + 1];
    float4 d0 = xp1[lane * 2];
    float4 d1 = xp1[lane * 2 + 1];

    // in-register inclusive prefixes (two independent chains)
    float p[8], q[8];
    p[0] = a0.x;        p[1] = p[0] + a0.y;
    p[2] = p[1] + a0.z; p[3] = p[2] + a0.w;
    p[4] = p[3] + a1.x; p[5] = p[4] + a1.y;
    p[6] = p[5] + a1.z; p[7] = p[6] + a1.w;
    q[0] = c0.x;        q[1] = q[0] + c0.y;
    q[2] = q[1] + c0.z; q[3] = q[2] + c0.w;
    q[4] = q[3] + c1.x; q[5] = q[4] + c1.y;
    q[6] = q[5] + c1.z; q[7] = q[6] + c1.w;

    // wave-inclusive scans of lane totals, interleaved
    float s = p[7], u = q[7];
    #pragma unroll
    for (int d = 1; d < 64; d <<= 1) {
        float t2 = __shfl_up(s, d, 64);
        float u2 = __shfl_up(u, d, 64);
        if (lane >= d) { s += t2; u += u2; }
    }
    float off0 = s - p[7];
    float off1 = u - q[7];

    float pf[8], qf[8];              // pf[j] = P[lane*8 + j + 1]
    #pragma unroll
    for (int j = 0; j < 8; ++j) { pf[j] = off0 + p[j]; qf[j] = off1 + q[j]; }

    float tot0 = __shfl(pf[7], 63, 64);
    float tot1 = __shfl(qf[7], 63, 64);

    float xv[8] = { b0.x, b0.y, b0.z, b0.w, b1.x, b1.y, b1.z, b1.w };
    float yv[8] = { d0.x, d0.y, d0.z, d0.w, d1.x, d1.y, d1.z, d1.w };

    float o0[8], o1[8];
    #pragma unroll
    for (int j = 0; j < 8; ++j) {
        // hi endpoint: P[w+RW+1] at lane l + (j+RW)/8, slot (j+RW)%8
        int hidx = j + RW;                 // 34..41
        int dhi  = hidx >> 3;              // 4 or 5
        int shi  = hidx & 7;
        float hv0 = __shfl_down(pf[shi], dhi, 64);
        float hv1 = __shfl_down(qf[shi], dhi, 64);
        bool hclip = (lane + dhi > 63);
        if (hclip) { hv0 = tot0; hv1 = tot1; }

        // lo endpoint: P[w-RW] at lane l + floor((j-RW-1)/8)
        int lidx = j - RW - 1;             // -35..-28
        int fl   = lidx >> 3;              // arithmetic shift = floor
        int dlo  = -fl;
        int slo  = lidx - fl * 8;          // 0..7
        float lv0 = __shfl_up(pf[slo], dlo, 64);
        float lv1 = __shfl_up(qf[slo], dlo, 64);
        bool lclip = (lane < dlo);
        if (lclip) { lv0 = 0.0f; lv1 = 0.0f; }

        o0[j] = (xv[j] - (hv0 - lv0) * INV) * 0.2f;
        o1[j] = (yv[j] - (hv1 - lv1) * INV) * 0.2f;
    }

    float4* op0 = (float4*)(out + base0);
    float4* op1 = (float4*)(out + base1);
    op0[lane * 2]     = make_float4(o0[0], o0[1], o0[2], o0[3]);
    op0[lane * 2 + 1] = make_float4(o0[4], o0[5], o0[6], o0[7]);
    op1[lane * 2]     = make_float4(o1[0], o1[1], o1[2], o1[3]);
    op1[lane * 2 + 1] = make_float4(o1[4], o1[5], o1[6], o1[7]);
}

extern "C" void kernel_launch(void* const* d_in, const int* in_sizes, int n_in,
                              void* d_out, int out_size, void* d_ws, size_t ws_size,
                              hipStream_t stream) {
    const float* x   = (const float*)d_in[0];
    float*       out = (float*)d_out;
    float*       tmp = (float*)d_ws;   // needs NIMG*HH*WW*4 = 32 MiB scratch

    int vthreads = NIMG * NCHUNK * W2;            // 262144
    vpass_kernel<<<vthreads / 256, 256, 0, stream>>>(x, tmp);

    int hthreads = (NIMG * HH / 2) * 64;          // 524288
    hpass_kernel<<<hthreads / 256, 256, 0, stream>>>(tmp, x, out);
}